// Round 2
// baseline (140264.014 us; speedup 1.0000x reference)
//
#include <hip/hip_runtime.h>
#include <math.h>

#define Bn 4096
#define Tn 128
#define Fn 96
#define Sn 128
#define Hn 512
#define RR 16   // batch rows per block in the step kernel

__device__ __forceinline__ float sigmf_(float x){ return 1.0f/(1.0f+expf(-x)); }

// ---------- prologue kernels ----------

// s_c = mask*statics + (1-mask)*(statics @ fr_W.T + fr_b)
__global__ void k_static(const float* __restrict__ statics, const float* __restrict__ smask,
                         const float* __restrict__ frW, const float* __restrict__ frb,
                         float* __restrict__ s_c){
  __shared__ float row[Sn];
  int b = blockIdx.x, j = threadIdx.x;   // blockDim = 128
  row[j] = statics[b*Sn + j];
  __syncthreads();
  float acc = frb[j];
  #pragma unroll 4
  for (int k = 0; k < Sn; k++) acc += row[k] * frW[j*Sn + k];
  float m = smask[b*Sn + j];
  s_c[b*Sn + j] = m * row[j] + (1.0f - m) * acc;
}

// out[b,n] = act(in[b,:] @ W[n,:] + bias[n]); safe in-place (row staged first)
template<int K, int N, bool RELU>
__global__ void k_mlp(const float* __restrict__ in, const float* __restrict__ W,
                      const float* __restrict__ bias, float* __restrict__ out){
  __shared__ float row[K];
  int b = blockIdx.x;
  for (int i = threadIdx.x; i < K; i += blockDim.x) row[i] = in[b*K + i];
  __syncthreads();
  for (int n = threadIdx.x; n < N; n += blockDim.x){
    float acc = bias[n];
    #pragma unroll 4
    for (int k = 0; k < K; k++) acc += row[k] * W[n*K + k];
    if (RELU) acc = fmaxf(acc, 0.0f);
    out[b*N + n] = acc;
  }
}

// den[t] = sum over (b,f) of masks[b,t,f]
__global__ void k_masksum(const float* __restrict__ masks, float* __restrict__ den){
  int t = blockIdx.x, tid = threadIdx.x;   // blockDim = 256
  float s = 0.f;
  for (int i = tid; i < Bn*Fn; i += 256){
    int b = i / Fn, f = i - b*Fn;
    s += masks[((size_t)b*Tn + t)*Fn + f];
  }
  __shared__ float red[256];
  red[tid] = s; __syncthreads();
  for (int o = 128; o > 0; o >>= 1){ if (tid < o) red[tid] += red[tid + o]; __syncthreads(); }
  if (tid == 0) den[t] = red[0];
}

// ---------- the sequential time-step kernel ----------
__global__ __launch_bounds__(512) void k_step(int t,
    const float* __restrict__ values, const float* __restrict__ masks, const float* __restrict__ deltas,
    const float* __restrict__ tdW,  const float* __restrict__ tdb,
    const float* __restrict__ histW, const float* __restrict__ histb,
    const float* __restrict__ realW, const float* __restrict__ realb,
    const float* __restrict__ stterm,
    const float* __restrict__ Wih, const float* __restrict__ Whh,
    const float* __restrict__ bih, const float* __restrict__ bhh,
    float* __restrict__ h_g, float* __restrict__ c_g,
    float* __restrict__ num, float* __restrict__ out_imp){
  __shared__ float sh_h [RR][Hn];   // 32 KB
  __shared__ float sh_x [RR][Fn];
  __shared__ float sh_m [RR][Fn];
  __shared__ float sh_d [RR][Fn];
  __shared__ float sh_cc[RR][Fn];
  __shared__ float wred[8];
  const int tid = threadIdx.x;        // 512 threads
  const int r0  = blockIdx.x * RR;

  // stage h and this step's x/m/d rows
  for (int i = tid; i < RR*Hn; i += 512) ((float*)sh_h)[i] = h_g[(size_t)r0*Hn + i];
  for (int i = tid; i < RR*Fn; i += 512){
    int r = i / Fn, f = i - r*Fn;
    size_t gi = ((size_t)(r0 + r)*Tn + t)*Fn + f;
    sh_x[r][f] = values[gi];
    sh_m[r][f] = masks[gi];
    sh_d[r][f] = deltas[gi];
  }
  __syncthreads();

  // gamma decay: h *= exp(-relu(d @ td_W.T + td_b))
  for (int i = tid; i < RR*Hn; i += 512){
    int r = i >> 9, j = i & (Hn - 1);
    float acc = tdb[j];
    const float* w = tdW + (size_t)j*Fn;
    #pragma unroll 4
    for (int k = 0; k < Fn; k++) acc += sh_d[r][k] * w[k];
    sh_h[r][j] *= expf(-fmaxf(acc, 0.0f));
  }
  __syncthreads();

  // x_c, imputations (= c_c !), c_c, x_loss numerator
  float lsum = 0.f;
  for (int i = tid; i < RR*Fn; i += 512){
    int r = i / Fn, f = i - r*Fn;
    int b = r0 + r;
    float acc = realb[f] + histb[f] + stterm[(size_t)b*Fn + f];
    const float* wr = realW + (size_t)f*Fn;
    #pragma unroll 4
    for (int k = 0; k < Fn; k++) acc += sh_x[r][k] * wr[k];
    const float* wh = histW + (size_t)f*Hn;
    #pragma unroll 4
    for (int k = 0; k < Hn; k++) acc += sh_h[r][k] * wh[k];
    float m = sh_m[r][f], x = sh_x[r][f];
    lsum += fabsf(x - acc) * m;
    float cc = m*x + (1.0f - m)*acc;
    sh_cc[r][f] = cc;
    out_imp[((size_t)b*Tn + t)*Fn + f] = cc;   // scan emits c_c, not x_c
  }
  #pragma unroll
  for (int o = 32; o > 0; o >>= 1) lsum += __shfl_down(lsum, o);
  if ((tid & 63) == 0) wred[tid >> 6] = lsum;
  __syncthreads();                       // also makes sh_cc visible
  if (tid == 0){
    float s = 0.f;
    #pragma unroll
    for (int w = 0; w < 8; w++) s += wred[w];
    atomicAdd(&num[t], s);
  }

  // LSTM gates: each thread owns one hidden column j for all RR rows.
  const int j = tid;                     // 512 threads == Hn
  float accA[RR], accB[RR], ci[RR];
  auto gatedot = [&](int g, float* acc){
    const int n = g*Hn + j;
    const float bb = bih[n] + bhh[n];
    #pragma unroll
    for (int r = 0; r < RR; r++) acc[r] = bb;
    const float* wih = Wih + (size_t)n*(2*Fn);
    #pragma unroll 2
    for (int k = 0; k < Fn; k++){
      float w = wih[k];
      #pragma unroll
      for (int r = 0; r < RR; r++) acc[r] += sh_cc[r][k] * w;
    }
    #pragma unroll 2
    for (int k = 0; k < Fn; k++){
      float w = wih[Fn + k];
      #pragma unroll
      for (int r = 0; r < RR; r++) acc[r] += sh_m[r][k] * w;
    }
    const float* whh = Whh + (size_t)n*Hn;
    #pragma unroll 2
    for (int k = 0; k < Hn; k++){
      float w = whh[k];
      #pragma unroll
      for (int r = 0; r < RR; r++) acc[r] += sh_h[r][k] * w;
    }
  };
  gatedot(2, accA);  // g (tanh input)
  gatedot(0, accB);  // i
  #pragma unroll
  for (int r = 0; r < RR; r++) ci[r] = sigmf_(accB[r]) * tanhf(accA[r]);
  gatedot(1, accA);  // f
  gatedot(3, accB);  // o
  #pragma unroll
  for (int r = 0; r < RR; r++){
    size_t idx = (size_t)(r0 + r)*Hn + j;
    float cn = sigmf_(accA[r]) * c_g[idx] + ci[r];
    c_g[idx] = cn;
    h_g[idx] = sigmf_(accB[r]) * tanhf(cn);
  }
}

// ---------- epilogue ----------

__global__ void k_out(const float* __restrict__ h_g, const float* __restrict__ outW,
                      const float* __restrict__ outb, const float* __restrict__ labels,
                      float* __restrict__ out_sig, float* __restrict__ yacc){
  int b = blockIdx.x, lane = threadIdx.x;  // blockDim = 64
  float s = 0.f;
  for (int k = lane; k < Hn; k += 64) s += h_g[(size_t)b*Hn + k] * outW[k];
  #pragma unroll
  for (int o = 32; o > 0; o >>= 1) s += __shfl_down(s, o);
  if (lane == 0){
    float z = s + outb[0];
    out_sig[b] = sigmf_(z);
    float yl = fmaxf(z, 0.f) - z*labels[b] + log1pf(expf(-fabsf(z)));
    atomicAdd(yacc, yl);
  }
}

__global__ void k_loss(const float* __restrict__ realW, const float* __restrict__ histW,
                       const float* __restrict__ stW,   const float* __restrict__ frW,
                       const float* __restrict__ num,   const float* __restrict__ den,
                       const float* __restrict__ yacc,  float* __restrict__ out0){
  int tid = threadIdx.x;   // 256
  float r1 = 0.f;
  for (int i = tid; i < Fn*Fn; i += 256) r1 += fabsf(realW[i]);
  for (int i = tid; i < Fn*Hn; i += 256) r1 += fabsf(histW[i]);
  for (int i = tid; i < Fn*Sn; i += 256) r1 += fabsf(stW[i]);
  float rd = 0.f;
  for (int i = tid; i < Fn; i += 256) rd += fabsf(realW[i*Fn + i]);
  float fd = 0.f;
  for (int i = tid; i < Sn; i += 256) fd += fabsf(frW[i*Sn + i]);
  float xl = 0.f;
  for (int t = tid; t < Tn; t += 256) xl += num[t] / (den[t] + 1e-5f);
  float v = 0.01f*r1 + 0.1f*rd + 0.3f*xl + 0.03f*fd;  // L1 + L2 diag + x_loss + s_loss
  __shared__ float red[256];
  red[tid] = v; __syncthreads();
  for (int o = 128; o > 0; o >>= 1){ if (tid < o) red[tid] += red[tid + o]; __syncthreads(); }
  if (tid == 0) out0[0] = red[0] + yacc[0] / (float)Bn;
}

// ---------- launch ----------

extern "C" void kernel_launch(void* const* d_in, const int* in_sizes, int n_in,
                              void* d_out, int out_size, void* d_ws, size_t ws_size,
                              hipStream_t stream){
  const float* values = (const float*)d_in[0];
  const float* masks  = (const float*)d_in[1];
  const float* deltas = (const float*)d_in[2];
  const float* statics= (const float*)d_in[3];
  const float* smask  = (const float*)d_in[4];
  const float* labels = (const float*)d_in[5];
  const float* frW = (const float*)d_in[6];
  const float* frb = (const float*)d_in[7];
  const float* d1W = (const float*)d_in[8];
  const float* d1b = (const float*)d_in[9];
  const float* d2W = (const float*)d_in[10];
  const float* d2b = (const float*)d_in[11];
  const float* d3W = (const float*)d_in[12];
  const float* d3b = (const float*)d_in[13];
  const float* tdW = (const float*)d_in[14];
  const float* tdb = (const float*)d_in[15];
  const float* histW = (const float*)d_in[16];
  const float* histb = (const float*)d_in[17];
  const float* stW = (const float*)d_in[18];
  const float* stb = (const float*)d_in[19];
  const float* realW = (const float*)d_in[20];
  const float* realb = (const float*)d_in[21];
  const float* Wih = (const float*)d_in[22];
  const float* Whh = (const float*)d_in[23];
  const float* bih = (const float*)d_in[24];
  const float* bhh = (const float*)d_in[25];
  const float* outW = (const float*)d_in[26];
  const float* outb = (const float*)d_in[27];

  float* out0    = (float*)d_out;
  float* out_sig = out0 + 1;
  float* out_imp = out0 + 1 + Bn;

  float* ws   = (float*)d_ws;
  float* s_c  = ws;  ws += Bn*Sn;
  float* h    = ws;  ws += (size_t)Bn*Hn;
  float* c    = ws;  ws += (size_t)Bn*Hn;
  float* st   = ws;  ws += Bn*Fn;
  float* tmp  = ws;  ws += (size_t)Bn*Hn;
  float* den  = ws;  ws += Tn;
  float* num  = ws;  ws += Tn;
  float* yacc = num + Tn;   // zeroed together with num

  hipMemsetAsync(c,   0, (size_t)Bn*Hn*sizeof(float), stream);
  hipMemsetAsync(num, 0, (Tn + 1)*sizeof(float), stream);

  k_static<<<Bn, Sn, 0, stream>>>(statics, smask, frW, frb, s_c);
  k_mlp<Sn, Hn, true ><<<Bn, 256, 0, stream>>>(s_c, d1W, d1b, tmp);
  k_mlp<Hn, Hn, true ><<<Bn, 256, 0, stream>>>(tmp, d2W, d2b, tmp);
  k_mlp<Hn, Hn, true ><<<Bn, 256, 0, stream>>>(tmp, d3W, d3b, h);
  k_mlp<Sn, Fn, false><<<Bn, 256, 0, stream>>>(s_c, stW, stb, st);
  k_masksum<<<Tn, 256, 0, stream>>>(masks, den);

  for (int t = 0; t < Tn; t++)
    k_step<<<Bn/RR, 512, 0, stream>>>(t, values, masks, deltas, tdW, tdb,
                                      histW, histb, realW, realb, st,
                                      Wih, Whh, bih, bhh, h, c, num, out_imp);

  k_out<<<Bn, 64, 0, stream>>>(h, outW, outb, labels, out_sig, yacc);
  k_loss<<<1, 256, 0, stream>>>(realW, histW, stW, frW, num, den, yacc, out0);
}

// Round 3
// 11281.779 us; speedup vs baseline: 12.4328x; 12.4328x over previous
//
#include <hip/hip_runtime.h>
#include <math.h>

#define Bn 4096
#define Tn 128
#define Fn 96
#define Sn 128
#define Hn 512

typedef __attribute__((ext_vector_type(8))) short bf16x8;
typedef __attribute__((ext_vector_type(4))) float f32x4;

#define GC(p) ((const __attribute__((address_space(1))) void*)(p))
#define LC(p) ((__attribute__((address_space(3))) void*)(p))

__device__ __forceinline__ short tobf(float f){
  unsigned u = __float_as_uint(f);
  unsigned r = (u + 0x7fffu + ((u>>16)&1u)) >> 16;
  return (short)r;
}
__device__ __forceinline__ float bf2f(short s){
  return __uint_as_float(((unsigned)(unsigned short)s)<<16);
}
__device__ __forceinline__ float sigmf_(float x){ return 1.0f/(1.0f+expf(-x)); }

// stage `rows` rows (64 bf16 = 128B each) from gsrc (row stride sstride shorts,
// start col k0) into LDS tile lt with chunk-XOR swizzle (chunk ^= row&7).
// Linear LDS dest + inverse-swizzled global source (both-sides rule).
__device__ __forceinline__ void stage_tile(const short* gsrc, size_t sstride, int k0,
                                           short* lt, int rows, int wid, int lane, int nw){
  int calls = rows >> 3;
  for (int c = wid; c < calls; c += nw){
    int r = (c<<3) + (lane>>3);
    int ch = (lane&7) ^ (r&7);
    const short* gp = gsrc + (size_t)r*sstride + k0 + (ch<<3);
    __builtin_amdgcn_global_load_lds(GC(gp), LC(lt + (c<<9)), 16, 0, 0);
  }
}
__device__ __forceinline__ bf16x8 frag(const short* lt, int row, int ch){
  return *(const bf16x8*)(lt + (row<<6) + ((ch ^ (row&7))<<3));
}

// ---------- prologue: weight prepack (fp32 -> bf16, padded/fused layouts) ----------

__global__ void k_pack_td(const float* __restrict__ tdW, short* __restrict__ tdWp){
  int i = blockIdx.x*256 + threadIdx.x;            // 512*128
  if (i >= 512*128) return;
  int n = i>>7, k = i&127;
  tdWp[i] = (k < Fn) ? tobf(tdW[n*Fn + k]) : (short)0;
}
__global__ void k_pack_x(const float* __restrict__ realW, const float* __restrict__ histW,
                         const float* __restrict__ realb, const float* __restrict__ histb,
                         short* __restrict__ Wxp, float* __restrict__ bxp){
  int i = blockIdx.x*256 + threadIdx.x;            // 96*640
  if (i < Fn) bxp[i] = realb[i] + histb[i];
  if (i >= Fn*640) return;
  int f = i/640, k = i - f*640;
  float v = 0.f;
  if (k < 96) v = realW[f*Fn + k];
  else if (k < 608) v = histW[f*Hn + (k-96)];
  Wxp[i] = tobf(v);
}
__global__ void k_pack_g(const float* __restrict__ Wih, const float* __restrict__ Whh,
                         const float* __restrict__ bih, const float* __restrict__ bhh,
                         short* __restrict__ Wgp, float* __restrict__ bgp){
  int i = blockIdx.x*256 + threadIdx.x;            // 8*256*704
  if (i >= 8*256*704) return;
  int k = i % 704; int nc = i / 704;
  int pb = nc >> 8, ncol = nc & 255;
  int jj = ncol >> 2, g = ncol & 3;
  int n = g*Hn + pb*64 + jj;
  float v;
  if (k < 512) v = Whh[(size_t)n*Hn + k];
  else if (k < 608) v = Wih[(size_t)n*192 + (k-512)];
  else v = Wih[(size_t)n*192 + 96 + (k-608)];
  Wgp[i] = tobf(v);
  if (k == 0) bgp[nc] = bih[n] + bhh[n];
}

// ---------- prologue math (unchanged fp32) ----------

__global__ void k_static(const float* __restrict__ statics, const float* __restrict__ smask,
                         const float* __restrict__ frW, const float* __restrict__ frb,
                         float* __restrict__ s_c){
  __shared__ float row[Sn];
  int b = blockIdx.x, j = threadIdx.x;
  row[j] = statics[b*Sn + j];
  __syncthreads();
  float acc = frb[j];
  #pragma unroll 4
  for (int k = 0; k < Sn; k++) acc += row[k] * frW[j*Sn + k];
  float m = smask[b*Sn + j];
  s_c[b*Sn + j] = m * row[j] + (1.0f - m) * acc;
}

template<int K, int N, bool RELU>
__global__ void k_mlp(const float* __restrict__ in, const float* __restrict__ W,
                      const float* __restrict__ bias, float* __restrict__ out){
  __shared__ float row[K];
  int b = blockIdx.x;
  for (int i = threadIdx.x; i < K; i += blockDim.x) row[i] = in[b*K + i];
  __syncthreads();
  for (int n = threadIdx.x; n < N; n += blockDim.x){
    float acc = bias[n];
    #pragma unroll 4
    for (int k = 0; k < K; k++) acc += row[k] * W[n*K + k];
    if (RELU) acc = fmaxf(acc, 0.0f);
    out[b*N + n] = acc;
  }
}

__global__ void k_masksum(const float* __restrict__ masks, float* __restrict__ den){
  int t = blockIdx.x, tid = threadIdx.x;
  float s = 0.f;
  for (int i = tid; i < Bn*Fn; i += 256){
    int b = i / Fn, f = i - b*Fn;
    s += masks[((size_t)b*Tn + t)*Fn + f];
  }
  __shared__ float red[256];
  red[tid] = s; __syncthreads();
  for (int o = 128; o > 0; o >>= 1){ if (tid < o) red[tid] += red[tid + o]; __syncthreads(); }
  if (tid == 0) den[t] = red[0];
}

// ---------- per-step kernel 1: decay (MFMA M=4096,N=512,K=96pad128) + x/m convert ----------
// h_dec = h * exp(-relu(d @ tdW^T + tdb)) -> bf16 inp[:,96:608]; x->inp[:,0:96], m->inp[:,704:800]
__global__ __launch_bounds__(512) void k_decay(int t,
    const float* __restrict__ values, const float* __restrict__ masks, const float* __restrict__ deltas,
    const short* __restrict__ tdWp, const float* __restrict__ tdb,
    const float* __restrict__ h_g, short* __restrict__ inp){
  __shared__ __align__(16) short lds[(128+128)*64];   // A [128][64], B [128][64]
  const int tid = threadIdx.x, lane = tid&63, wid = tid>>6;
  const int mb = blockIdx.x >> 2, nb = blockIdx.x & 3;
  const int r0 = mb*128;
  short* lA = lds;
  short* lB = lds + 128*64;

  if (nb == 0){  // convert this slab's x,m to bf16
    for (int i = tid; i < 128*Fn; i += 512){
      int r = i/Fn, f = i - r*Fn; int row = r0 + r;
      size_t gi = ((size_t)row*Tn + t)*Fn + f;
      inp[(size_t)row*800 + f]       = tobf(values[gi]);
      inp[(size_t)row*800 + 704 + f] = tobf(masks[gi]);
    }
  }

  const int wr0 = (wid>>2)*64, wc0 = (wid&3)*32;
  f32x4 acc[4][2];
  #pragma unroll
  for (int m=0;m<4;m++){ acc[m][0]=(f32x4){0,0,0,0}; acc[m][1]=(f32x4){0,0,0,0}; }

  for (int kt=0; kt<2; kt++){
    if (kt) __syncthreads();
    // reg-stage deltas (fp32 global -> bf16 LDS, swizzled write)
    int k0 = kt*64;
    #pragma unroll
    for (int q=0;q<2;q++){
      int cid = tid + q*512;            // 1024 chunks: 128 rows x 8
      int r = cid>>3, cl = cid&7;
      int kbase = k0 + cl*8;
      bf16x8 vv = {0,0,0,0,0,0,0,0};
      if (kbase < Fn){
        const float4* gp = (const float4*)(deltas + ((size_t)(r0+r)*Tn + t)*Fn + kbase);
        float4 u0 = gp[0], u1 = gp[1];
        vv[0]=tobf(u0.x); vv[1]=tobf(u0.y); vv[2]=tobf(u0.z); vv[3]=tobf(u0.w);
        vv[4]=tobf(u1.x); vv[5]=tobf(u1.y); vv[6]=tobf(u1.z); vv[7]=tobf(u1.w);
      }
      *(bf16x8*)(lA + (r<<6) + ((cl ^ (r&7))<<3)) = vv;
    }
    stage_tile(tdWp + (size_t)(nb*128)*128, 128, k0, lB, 128, wid, lane, 8);
    __syncthreads();
    #pragma unroll
    for (int kk=0;kk<2;kk++){
      bf16x8 af[4], bfr[2];
      int ch = (kk<<2) + (lane>>4);
      #pragma unroll
      for (int m=0;m<4;m++) af[m] = frag(lA, wr0 + m*16 + (lane&15), ch);
      #pragma unroll
      for (int n=0;n<2;n++) bfr[n] = frag(lB, wc0 + n*16 + (lane&15), ch);
      #pragma unroll
      for (int m=0;m<4;m++)
        #pragma unroll
        for (int n=0;n<2;n++)
          acc[m][n] = __builtin_amdgcn_mfma_f32_16x16x32_bf16(af[m], bfr[n], acc[m][n], 0,0,0);
    }
  }
  #pragma unroll
  for (int m=0;m<4;m++)
    #pragma unroll
    for (int n=0;n<2;n++)
      #pragma unroll
      for (int reg=0;reg<4;reg++){
        int row = r0 + wr0 + m*16 + ((lane>>4)<<2) + reg;
        int jh  = nb*128 + wc0 + n*16 + (lane&15);
        float v = acc[m][n][reg] + tdb[jh];
        float gam = __expf(-fmaxf(v, 0.f));
        float hd = h_g[(size_t)row*Hn + jh] * gam;
        inp[(size_t)row*800 + 96 + jh] = tobf(hd);
      }
}

// ---------- per-step kernel 2: x_c GEMM (M=4096,N=96,K=608pad640) + c_c + loss ----------
__global__ __launch_bounds__(256) void k_xc(int t,
    const short* __restrict__ Wxp, const float* __restrict__ bxp,
    const float* __restrict__ st, short* __restrict__ inp,
    float* __restrict__ out_imp, float* __restrict__ num){
  __shared__ __align__(16) short lds[(64+96)*64];     // A [64][64], B [96][64]
  __shared__ float wred[4];
  const int tid = threadIdx.x, lane = tid&63, wid = tid>>6;
  const int r0 = blockIdx.x*64;
  short* lA = lds;
  short* lB = lds + 64*64;
  const int wr0 = (wid>>1)*32, wc0 = (wid&1)*48;
  f32x4 acc[2][3];
  #pragma unroll
  for (int m=0;m<2;m++)
    #pragma unroll
    for (int n=0;n<3;n++) acc[m][n] = (f32x4){0,0,0,0};

  for (int kt=0; kt<10; kt++){
    if (kt) __syncthreads();
    stage_tile(inp + (size_t)r0*800, 800, kt*64, lA, 64, wid, lane, 4);
    stage_tile(Wxp, 640, kt*64, lB, 96, wid, lane, 4);
    __syncthreads();
    #pragma unroll
    for (int kk=0;kk<2;kk++){
      bf16x8 af[2], bfr[3];
      int ch = (kk<<2) + (lane>>4);
      #pragma unroll
      for (int m=0;m<2;m++) af[m] = frag(lA, wr0 + m*16 + (lane&15), ch);
      #pragma unroll
      for (int n=0;n<3;n++) bfr[n] = frag(lB, wc0 + n*16 + (lane&15), ch);
      #pragma unroll
      for (int m=0;m<2;m++)
        #pragma unroll
        for (int n=0;n<3;n++)
          acc[m][n] = __builtin_amdgcn_mfma_f32_16x16x32_bf16(af[m], bfr[n], acc[m][n], 0,0,0);
    }
  }
  float lsum = 0.f;
  float bxv[3];
  #pragma unroll
  for (int n=0;n<3;n++) bxv[n] = bxp[wc0 + n*16 + (lane&15)];
  #pragma unroll
  for (int m=0;m<2;m++)
    #pragma unroll
    for (int n=0;n<3;n++)
      #pragma unroll
      for (int reg=0;reg<4;reg++){
        int row = r0 + wr0 + m*16 + ((lane>>4)<<2) + reg;
        int f   = wc0 + n*16 + (lane&15);
        float xc = acc[m][n][reg] + bxv[n] + st[(size_t)row*Fn + f];
        float xv = bf2f(inp[(size_t)row*800 + f]);
        float mv = bf2f(inp[(size_t)row*800 + 704 + f]);
        lsum += fabsf(xv - xc)*mv;
        float cc = mv*xv + (1.f-mv)*xc;
        inp[(size_t)row*800 + 608 + f] = tobf(cc);
        out_imp[((size_t)row*Tn + t)*Fn + f] = cc;
      }
  #pragma unroll
  for (int o=32;o>0;o>>=1) lsum += __shfl_down(lsum, o);
  if (lane==0) wred[wid] = lsum;
  __syncthreads();
  if (tid==0) atomicAdd(&num[t], wred[0]+wred[1]+wred[2]+wred[3]);
}

// ---------- per-step kernel 3: gates GEMM (M=4096,N=2048,K=704) + fused LSTM update ----------
__global__ __launch_bounds__(256) void k_gates(int t, const short* __restrict__ inp,
    const short* __restrict__ Wgp, const float* __restrict__ bgp,
    float* __restrict__ h_g, float* __restrict__ c_g){
  __shared__ __align__(16) short lds[(64+256)*64];    // A [64][64], B [256][64]
  const int tid = threadIdx.x, lane = tid&63, wid = tid>>6;
  const int mb = blockIdx.x >> 3, pb = blockIdx.x & 7;
  const int r0 = mb*64;
  short* lA = lds;
  short* lB = lds + 64*64;
  const short* gB = Wgp + (size_t)pb*256*704;
  const int wc0 = wid*64;
  f32x4 acc[4][4];
  #pragma unroll
  for (int m=0;m<4;m++)
    #pragma unroll
    for (int n=0;n<4;n++) acc[m][n] = (f32x4){0,0,0,0};

  for (int kt=0; kt<11; kt++){
    if (kt) __syncthreads();
    stage_tile(inp + (size_t)r0*800 + 96, 800, kt*64, lA, 64, wid, lane, 4);
    stage_tile(gB, 704, kt*64, lB, 256, wid, lane, 4);
    __syncthreads();
    #pragma unroll
    for (int kk=0;kk<2;kk++){
      bf16x8 af[4], bfr[4];
      int ch = (kk<<2) + (lane>>4);
      #pragma unroll
      for (int m=0;m<4;m++) af[m] = frag(lA, m*16 + (lane&15), ch);
      #pragma unroll
      for (int n=0;n<4;n++) bfr[n] = frag(lB, wc0 + n*16 + (lane&15), ch);
      #pragma unroll
      for (int m=0;m<4;m++)
        #pragma unroll
        for (int n=0;n<4;n++)
          acc[m][n] = __builtin_amdgcn_mfma_f32_16x16x32_bf16(af[m], bfr[n], acc[m][n], 0,0,0);
    }
  }
  // fused LSTM update: gates interleaved as ncol = jj*4 + g; 4-lane shfl transpose.
  const int g = lane&3;
  float bgv[4];
  #pragma unroll
  for (int n=0;n<4;n++) bgv[n] = bgp[pb*256 + wc0 + n*16 + (lane&15)];
  const float s  = (g==2) ? 2.0f : -1.0f;   // exp arg scale: tanh uses e^{2x}, sigmoid e^{-x}
  const float ca = (g==2) ? -2.0f : 1.0f;   // r = q*ca + cb
  const float cb = (g==2) ? 1.0f : 0.0f;
  #pragma unroll
  for (int m=0;m<4;m++){
    int row = r0 + m*16 + ((lane>>4)<<2) + g;   // this lane owns acc-reg index g after transpose
    #pragma unroll
    for (int n=0;n<4;n++){
      float b = bgv[n];
      float q0 = 1.f/(1.f+__expf(s*(acc[m][n][0]+b))); float a0 = q0*ca+cb;
      float q1 = 1.f/(1.f+__expf(s*(acc[m][n][1]+b))); float a1 = q1*ca+cb;
      float q2 = 1.f/(1.f+__expf(s*(acc[m][n][2]+b))); float a2 = q2*ca+cb;
      float q3 = 1.f/(1.f+__expf(s*(acc[m][n][3]+b))); float a3 = q3*ca+cb;
      // lane p sends nonlin of its reg (p&3)^mask; receiver q gets gate (q&3)^mask of row-reg q&3
      int i1=g^1, i2=g^2, i3=g^3;
      float p1 = (i1==0)?a0:(i1==1)?a1:(i1==2)?a2:a3;
      float p2 = (i2==0)?a0:(i2==1)?a1:(i2==2)?a2:a3;
      float p3 = (i3==0)?a0:(i3==1)?a1:(i3==2)?a2:a3;
      float ow = (g==0)?a0:(g==1)?a1:(g==2)?a2:a3;
      float t1 = __shfl_xor(p1, 1, 64);
      float t2 = __shfl_xor(p2, 2, 64);
      float t3 = __shfl_xor(p3, 3, 64);
      float si = (g==0)?ow:(g==1)?t1:(g==2)?t2:t3;
      float sf = (g==1)?ow:(g==0)?t1:(g==3)?t2:t3;
      float tg = (g==2)?ow:(g==3)?t1:(g==0)?t2:t3;
      float so = (g==3)?ow:(g==2)?t1:(g==1)?t2:t3;
      int jh = pb*64 + ((wc0 + n*16 + (lane&15))>>2);
      size_t idx = (size_t)row*Hn + jh;
      float co = c_g[idx];
      float cn = sf*co + si*tg;
      float targ = fminf(fmaxf(2.0f*cn,-60.f),60.f);
      float e = __expf(targ); float th = (e-1.f)/(e+1.f);
      c_g[idx] = cn;
      h_g[idx] = so*th;
    }
  }
}

// ---------- epilogue ----------

__global__ void k_out(const float* __restrict__ h_g, const float* __restrict__ outW,
                      const float* __restrict__ outb, const float* __restrict__ labels,
                      float* __restrict__ out_sig, float* __restrict__ yacc){
  int b = blockIdx.x, lane = threadIdx.x;
  float s = 0.f;
  for (int k = lane; k < Hn; k += 64) s += h_g[(size_t)b*Hn + k] * outW[k];
  #pragma unroll
  for (int o = 32; o > 0; o >>= 1) s += __shfl_down(s, o);
  if (lane == 0){
    float z = s + outb[0];
    out_sig[b] = sigmf_(z);
    float yl = fmaxf(z, 0.f) - z*labels[b] + log1pf(expf(-fabsf(z)));
    atomicAdd(yacc, yl);
  }
}

__global__ void k_loss(const float* __restrict__ realW, const float* __restrict__ histW,
                       const float* __restrict__ stW,   const float* __restrict__ frW,
                       const float* __restrict__ num,   const float* __restrict__ den,
                       const float* __restrict__ yacc,  float* __restrict__ out0){
  int tid = threadIdx.x;
  float r1 = 0.f;
  for (int i = tid; i < Fn*Fn; i += 256) r1 += fabsf(realW[i]);
  for (int i = tid; i < Fn*Hn; i += 256) r1 += fabsf(histW[i]);
  for (int i = tid; i < Fn*Sn; i += 256) r1 += fabsf(stW[i]);
  float rd = 0.f;
  for (int i = tid; i < Fn; i += 256) rd += fabsf(realW[i*Fn + i]);
  float fd = 0.f;
  for (int i = tid; i < Sn; i += 256) fd += fabsf(frW[i*Sn + i]);
  float xl = 0.f;
  for (int t = tid; t < Tn; t += 256) xl += num[t] / (den[t] + 1e-5f);
  float v = 0.01f*r1 + 0.1f*rd + 0.3f*xl + 0.03f*fd;
  __shared__ float red[256];
  red[tid] = v; __syncthreads();
  for (int o = 128; o > 0; o >>= 1){ if (tid < o) red[tid] += red[tid + o]; __syncthreads(); }
  if (tid == 0) out0[0] = red[0] + yacc[0] / (float)Bn;
}

// ---------- launch ----------

extern "C" void kernel_launch(void* const* d_in, const int* in_sizes, int n_in,
                              void* d_out, int out_size, void* d_ws, size_t ws_size,
                              hipStream_t stream){
  const float* values = (const float*)d_in[0];
  const float* masks  = (const float*)d_in[1];
  const float* deltas = (const float*)d_in[2];
  const float* statics= (const float*)d_in[3];
  const float* smask  = (const float*)d_in[4];
  const float* labels = (const float*)d_in[5];
  const float* frW = (const float*)d_in[6];
  const float* frb = (const float*)d_in[7];
  const float* d1W = (const float*)d_in[8];
  const float* d1b = (const float*)d_in[9];
  const float* d2W = (const float*)d_in[10];
  const float* d2b = (const float*)d_in[11];
  const float* d3W = (const float*)d_in[12];
  const float* d3b = (const float*)d_in[13];
  const float* tdW = (const float*)d_in[14];
  const float* tdb = (const float*)d_in[15];
  const float* histW = (const float*)d_in[16];
  const float* histb = (const float*)d_in[17];
  const float* stW = (const float*)d_in[18];
  const float* stb = (const float*)d_in[19];
  const float* realW = (const float*)d_in[20];
  const float* realb = (const float*)d_in[21];
  const float* Wih = (const float*)d_in[22];
  const float* Whh = (const float*)d_in[23];
  const float* bih = (const float*)d_in[24];
  const float* bhh = (const float*)d_in[25];
  const float* outW = (const float*)d_in[26];
  const float* outb = (const float*)d_in[27];

  float* out0    = (float*)d_out;
  float* out_sig = out0 + 1;
  float* out_imp = out0 + 1 + Bn;

  float* wsf  = (float*)d_ws;
  float* s_c  = wsf;  wsf += Bn*Sn;
  float* h    = wsf;  wsf += (size_t)Bn*Hn;
  float* c    = wsf;  wsf += (size_t)Bn*Hn;
  float* st   = wsf;  wsf += Bn*Fn;
  float* tmp  = wsf;  wsf += (size_t)Bn*Hn;
  float* den  = wsf;  wsf += Tn;
  float* num  = wsf;  wsf += Tn;
  float* yacc = num + Tn;           // [1], contiguous with num for one memset
  wsf += 1;
  float* bxp  = wsf;  wsf += 128;   // 96 used
  float* bgp  = wsf;  wsf += 2048;
  // short region (16B aligned: all offsets above are multiples of 4 floats; force align)
  size_t off = ((size_t)(wsf - (float*)d_ws) + 3u) & ~(size_t)3u;
  short* wss  = (short*)((float*)d_ws + off);
  short* tdWp = wss;  wss += 512*128;
  short* Wxp  = wss;  wss += 96*640;
  short* Wgp  = wss;  wss += (size_t)8*256*704;
  short* inp  = wss;  wss += (size_t)Bn*800;

  hipMemsetAsync(c,   0, (size_t)Bn*Hn*sizeof(float), stream);
  hipMemsetAsync(num, 0, (Tn + 1)*sizeof(float), stream);

  // prepacks
  k_pack_td<<<(512*128+255)/256, 256, 0, stream>>>(tdW, tdWp);
  k_pack_x <<<(96*640+255)/256, 256, 0, stream>>>(realW, histW, realb, histb, Wxp, bxp);
  k_pack_g <<<(8*256*704+255)/256, 256, 0, stream>>>(Wih, Whh, bih, bhh, Wgp, bgp);

  // prologue math
  k_static<<<Bn, Sn, 0, stream>>>(statics, smask, frW, frb, s_c);
  k_mlp<Sn, Hn, true ><<<Bn, 256, 0, stream>>>(s_c, d1W, d1b, tmp);
  k_mlp<Hn, Hn, true ><<<Bn, 256, 0, stream>>>(tmp, d2W, d2b, tmp);
  k_mlp<Hn, Hn, true ><<<Bn, 256, 0, stream>>>(tmp, d3W, d3b, h);
  k_mlp<Sn, Fn, false><<<Bn, 256, 0, stream>>>(s_c, stW, stb, st);
  k_masksum<<<Tn, 256, 0, stream>>>(masks, den);

  for (int t = 0; t < Tn; t++){
    k_decay<<<(Bn/128)*4, 512, 0, stream>>>(t, values, masks, deltas, tdWp, tdb, h, inp);
    k_xc   <<<Bn/64,      256, 0, stream>>>(t, Wxp, bxp, st, inp, out_imp, num);
    k_gates<<<(Bn/64)*8,  256, 0, stream>>>(t, inp, Wgp, bgp, h, c);
  }

  k_out<<<Bn, 64, 0, stream>>>(h, outW, outb, labels, out_sig, yacc);
  k_loss<<<1, 256, 0, stream>>>(realW, histW, stW, frW, num, den, yacc, out0);
}

// Round 4
// 10866.644 us; speedup vs baseline: 12.9078x; 1.0382x over previous
//
#include <hip/hip_runtime.h>
#include <math.h>

#define Bn 4096
#define Tn 128
#define Fn 96
#define Sn 128
#define Hn 512

typedef __attribute__((ext_vector_type(8))) short bf16x8;
typedef __attribute__((ext_vector_type(4))) float f32x4;

#define GC(p) ((const __attribute__((address_space(1))) void*)(p))
#define LC(p) ((__attribute__((address_space(3))) void*)(p))

__device__ __forceinline__ short tobf(float f){
  unsigned u = __float_as_uint(f);
  unsigned r = (u + 0x7fffu + ((u>>16)&1u)) >> 16;
  return (short)r;
}
__device__ __forceinline__ float bf2f(short s){
  return __uint_as_float(((unsigned)(unsigned short)s)<<16);
}
__device__ __forceinline__ float sigmf_(float x){ return 1.0f/(1.0f+expf(-x)); }

// stage `rows` rows (64 bf16 = 128B each) from gsrc (row stride sstride shorts,
// start col k0) into LDS tile lt with chunk-XOR swizzle (chunk ^= row&7).
// Linear LDS dest + inverse-swizzled global source (both-sides rule).
__device__ __forceinline__ void stage_tile(const short* gsrc, size_t sstride, int k0,
                                           short* lt, int rows, int wid, int lane, int nw){
  int calls = rows >> 3;
  for (int c = wid; c < calls; c += nw){
    int r = (c<<3) + (lane>>3);
    int ch = (lane&7) ^ (r&7);
    const short* gp = gsrc + (size_t)r*sstride + k0 + (ch<<3);
    __builtin_amdgcn_global_load_lds(GC(gp), LC(lt + (c<<9)), 16, 0, 0);
  }
}
__device__ __forceinline__ bf16x8 frag(const short* lt, int row, int ch){
  return *(const bf16x8*)(lt + (row<<6) + ((ch ^ (row&7))<<3));
}

// ---------- prologue: weight prepack (fp32 -> bf16, padded/fused layouts) ----------

__global__ void k_pack_td(const float* __restrict__ tdW, short* __restrict__ tdWp){
  int i = blockIdx.x*256 + threadIdx.x;            // 512*128
  if (i >= 512*128) return;
  int n = i>>7, k = i&127;
  tdWp[i] = (k < Fn) ? tobf(tdW[n*Fn + k]) : (short)0;
}
__global__ void k_pack_x(const float* __restrict__ realW, const float* __restrict__ histW,
                         const float* __restrict__ realb, const float* __restrict__ histb,
                         short* __restrict__ Wxp, float* __restrict__ bxp){
  int i = blockIdx.x*256 + threadIdx.x;            // 96*640
  if (i < Fn) bxp[i] = realb[i] + histb[i];
  if (i >= Fn*640) return;
  int f = i/640, k = i - f*640;
  float v = 0.f;
  if (k < 96) v = realW[f*Fn + k];
  else if (k < 608) v = histW[f*Hn + (k-96)];
  Wxp[i] = tobf(v);
}
__global__ void k_pack_g(const float* __restrict__ Wih, const float* __restrict__ Whh,
                         const float* __restrict__ bih, const float* __restrict__ bhh,
                         short* __restrict__ Wgp, float* __restrict__ bgp){
  int i = blockIdx.x*256 + threadIdx.x;            // 8*256*704
  if (i >= 8*256*704) return;
  int k = i % 704; int nc = i / 704;
  int pb = nc >> 8, ncol = nc & 255;
  int jj = ncol >> 2, g = ncol & 3;
  int n = g*Hn + pb*64 + jj;
  float v;
  if (k < 512) v = Whh[(size_t)n*Hn + k];
  else if (k < 608) v = Wih[(size_t)n*192 + (k-512)];
  else v = Wih[(size_t)n*192 + 96 + (k-608)];
  Wgp[i] = tobf(v);
  if (k == 0) bgp[nc] = bih[n] + bhh[n];
}

// ---------- prologue math (fp32) ----------

__global__ void k_static(const float* __restrict__ statics, const float* __restrict__ smask,
                         const float* __restrict__ frW, const float* __restrict__ frb,
                         float* __restrict__ s_c){
  __shared__ float row[Sn];
  int b = blockIdx.x, j = threadIdx.x;
  row[j] = statics[b*Sn + j];
  __syncthreads();
  float acc = frb[j];
  #pragma unroll 4
  for (int k = 0; k < Sn; k++) acc += row[k] * frW[j*Sn + k];
  float m = smask[b*Sn + j];
  s_c[b*Sn + j] = m * row[j] + (1.0f - m) * acc;
}

template<int K, int N, bool RELU>
__global__ void k_mlp(const float* __restrict__ in, const float* __restrict__ W,
                      const float* __restrict__ bias, float* __restrict__ out){
  __shared__ float row[K];
  int b = blockIdx.x;
  for (int i = threadIdx.x; i < K; i += blockDim.x) row[i] = in[b*K + i];
  __syncthreads();
  for (int n = threadIdx.x; n < N; n += blockDim.x){
    float acc = bias[n];
    #pragma unroll 4
    for (int k = 0; k < K; k++) acc += row[k] * W[n*K + k];
    if (RELU) acc = fmaxf(acc, 0.0f);
    out[b*N + n] = acc;
  }
}

__global__ void k_masksum(const float* __restrict__ masks, float* __restrict__ den){
  int t = blockIdx.x, tid = threadIdx.x;
  float s = 0.f;
  for (int i = tid; i < Bn*Fn; i += 256){
    int b = i / Fn, f = i - b*Fn;
    s += masks[((size_t)b*Tn + t)*Fn + f];
  }
  __shared__ float red[256];
  red[tid] = s; __syncthreads();
  for (int o = 128; o > 0; o >>= 1){ if (tid < o) red[tid] += red[tid + o]; __syncthreads(); }
  if (tid == 0) den[t] = red[0];
}

// ---------- per-step kernel 1: decay (MFMA M=4096,N=512,K=96pad128) + x/m convert ----------
__global__ __launch_bounds__(512) void k_decay(int t,
    const float* __restrict__ values, const float* __restrict__ masks, const float* __restrict__ deltas,
    const short* __restrict__ tdWp, const float* __restrict__ tdb,
    const float* __restrict__ h_g, short* __restrict__ inp){
  __shared__ __align__(16) short lds[(128+128)*64];   // A [128][64], B [128][64]
  const int tid = threadIdx.x, lane = tid&63, wid = tid>>6;
  const int mb = blockIdx.x >> 2, nb = blockIdx.x & 3;
  const int r0 = mb*128;
  short* lA = lds;
  short* lB = lds + 128*64;

  if (nb == 0){  // convert this slab's x,m to bf16
    for (int i = tid; i < 128*Fn; i += 512){
      int r = i/Fn, f = i - r*Fn; int row = r0 + r;
      size_t gi = ((size_t)row*Tn + t)*Fn + f;
      inp[(size_t)row*800 + f]       = tobf(values[gi]);
      inp[(size_t)row*800 + 704 + f] = tobf(masks[gi]);
    }
  }

  const int wr0 = (wid>>2)*64, wc0 = (wid&3)*32;
  f32x4 acc[4][2];
  #pragma unroll
  for (int m=0;m<4;m++){ acc[m][0]=(f32x4){0,0,0,0}; acc[m][1]=(f32x4){0,0,0,0}; }

  for (int kt=0; kt<2; kt++){
    if (kt) __syncthreads();
    int k0 = kt*64;
    #pragma unroll
    for (int q=0;q<2;q++){
      int cid = tid + q*512;            // 1024 chunks: 128 rows x 8
      int r = cid>>3, cl = cid&7;
      int kbase = k0 + cl*8;
      bf16x8 vv = {0,0,0,0,0,0,0,0};
      if (kbase < Fn){
        const float4* gp = (const float4*)(deltas + ((size_t)(r0+r)*Tn + t)*Fn + kbase);
        float4 u0 = gp[0], u1 = gp[1];
        vv[0]=tobf(u0.x); vv[1]=tobf(u0.y); vv[2]=tobf(u0.z); vv[3]=tobf(u0.w);
        vv[4]=tobf(u1.x); vv[5]=tobf(u1.y); vv[6]=tobf(u1.z); vv[7]=tobf(u1.w);
      }
      *(bf16x8*)(lA + (r<<6) + ((cl ^ (r&7))<<3)) = vv;
    }
    stage_tile(tdWp + (size_t)(nb*128)*128, 128, k0, lB, 128, wid, lane, 8);
    __syncthreads();
    #pragma unroll
    for (int kk=0;kk<2;kk++){
      bf16x8 af[4], bfr[2];
      int ch = (kk<<2) + (lane>>4);
      #pragma unroll
      for (int m=0;m<4;m++) af[m] = frag(lA, wr0 + m*16 + (lane&15), ch);
      #pragma unroll
      for (int n=0;n<2;n++) bfr[n] = frag(lB, wc0 + n*16 + (lane&15), ch);
      #pragma unroll
      for (int m=0;m<4;m++)
        #pragma unroll
        for (int n=0;n<2;n++)
          acc[m][n] = __builtin_amdgcn_mfma_f32_16x16x32_bf16(af[m], bfr[n], acc[m][n], 0,0,0);
    }
  }
  #pragma unroll
  for (int m=0;m<4;m++)
    #pragma unroll
    for (int n=0;n<2;n++)
      #pragma unroll
      for (int reg=0;reg<4;reg++){
        int row = r0 + wr0 + m*16 + ((lane>>4)<<2) + reg;
        int jh  = nb*128 + wc0 + n*16 + (lane&15);
        float v = acc[m][n][reg] + tdb[jh];
        float gam = __expf(-fmaxf(v, 0.f));
        float hd = h_g[(size_t)row*Hn + jh] * gam;
        inp[(size_t)row*800 + 96 + jh] = tobf(hd);
      }
}

// ---------- per-step kernel 2: x_c GEMM (M=4096,N=96,K=608pad640), 32 rows/block ----------
__global__ __launch_bounds__(256) void k_xc(int t,
    const short* __restrict__ Wxp, const float* __restrict__ bxp,
    const float* __restrict__ st, short* __restrict__ inp,
    float* __restrict__ out_imp, float* __restrict__ num){
  __shared__ __align__(16) short lds[(32+96)*64];     // A [32][64], B [96][64]
  __shared__ float wred[4];
  const int tid = threadIdx.x, lane = tid&63, wid = tid>>6;
  const int r0 = blockIdx.x*32;
  short* lA = lds;
  short* lB = lds + 32*64;
  const int wr0 = (wid>>1)*16, wc0 = (wid&1)*48;
  f32x4 acc[3];
  #pragma unroll
  for (int n=0;n<3;n++) acc[n] = (f32x4){0,0,0,0};

  for (int kt=0; kt<10; kt++){
    if (kt) __syncthreads();
    stage_tile(inp + (size_t)r0*800, 800, kt*64, lA, 32, wid, lane, 4);
    stage_tile(Wxp, 640, kt*64, lB, 96, wid, lane, 4);
    __syncthreads();
    #pragma unroll
    for (int kk=0;kk<2;kk++){
      bf16x8 af; bf16x8 bfr[3];
      int ch = (kk<<2) + (lane>>4);
      af = frag(lA, wr0 + (lane&15), ch);
      #pragma unroll
      for (int n=0;n<3;n++) bfr[n] = frag(lB, wc0 + n*16 + (lane&15), ch);
      #pragma unroll
      for (int n=0;n<3;n++)
        acc[n] = __builtin_amdgcn_mfma_f32_16x16x32_bf16(af, bfr[n], acc[n], 0,0,0);
    }
  }
  float lsum = 0.f;
  float bxv[3];
  #pragma unroll
  for (int n=0;n<3;n++) bxv[n] = bxp[wc0 + n*16 + (lane&15)];
  #pragma unroll
  for (int n=0;n<3;n++)
    #pragma unroll
    for (int reg=0;reg<4;reg++){
      int row = r0 + wr0 + ((lane>>4)<<2) + reg;
      int f   = wc0 + n*16 + (lane&15);
      float xc = acc[n][reg] + bxv[n] + st[(size_t)row*Fn + f];
      float xv = bf2f(inp[(size_t)row*800 + f]);
      float mv = bf2f(inp[(size_t)row*800 + 704 + f]);
      lsum += fabsf(xv - xc)*mv;
      float cc = mv*xv + (1.f-mv)*xc;
      inp[(size_t)row*800 + 608 + f] = tobf(cc);
      out_imp[((size_t)row*Tn + t)*Fn + f] = cc;
    }
  #pragma unroll
  for (int o=32;o>0;o>>=1) lsum += __shfl_down(lsum, o);
  if (lane==0) wred[wid] = lsum;
  __syncthreads();
  if (tid==0) atomicAdd(&num[t], wred[0]+wred[1]+wred[2]+wred[3]);
}

// ---------- per-step kernel 3: gates GEMM (M=4096,N=2048,K=704) + fused LSTM ----------
// 128x256 tile, 8 waves, double-buffered LDS with issue-early prefetch (T3 minimum).
__global__ __launch_bounds__(512) void k_gates(int t, const short* __restrict__ inp,
    const short* __restrict__ Wgp, const float* __restrict__ bgp,
    float* __restrict__ h_g, float* __restrict__ c_g){
  __shared__ __align__(16) short lds[2][(128+256)*64];   // 96 KB double buffer
  const int tid = threadIdx.x, lane = tid&63, wid = tid>>6;
  const int mb = blockIdx.x >> 3, pb = blockIdx.x & 7;   // pb == XCD id -> B-panel L2-local
  const int r0 = mb*128;
  const short* gA = inp + (size_t)r0*800 + 96;
  const short* gB = Wgp + (size_t)pb*256*704;
  const int wr = (wid>>2)*64, wc = (wid&3)*64;
  f32x4 acc[4][4];
  #pragma unroll
  for (int m=0;m<4;m++)
    #pragma unroll
    for (int n=0;n<4;n++) acc[m][n] = (f32x4){0,0,0,0};

  stage_tile(gA, 800, 0, lds[0], 128, wid, lane, 8);
  stage_tile(gB, 704, 0, lds[0] + 128*64, 256, wid, lane, 8);
  __syncthreads();

  for (int kt=0; kt<11; kt++){
    const short* lA = lds[kt&1];
    const short* lB = lA + 128*64;
    if (kt < 10){   // issue next K-tile's loads BEFORE compute (prefetch)
      short* nxt = lds[(kt&1)^1];
      stage_tile(gA, 800, (kt+1)*64, nxt, 128, wid, lane, 8);
      stage_tile(gB, 704, (kt+1)*64, nxt + 128*64, 256, wid, lane, 8);
    }
    #pragma unroll
    for (int kk=0;kk<2;kk++){
      bf16x8 af[4], bfr[4];
      int ch = (kk<<2) + (lane>>4);
      #pragma unroll
      for (int m=0;m<4;m++) af[m] = frag(lA, wr + m*16 + (lane&15), ch);
      #pragma unroll
      for (int n=0;n<4;n++) bfr[n] = frag(lB, wc + n*16 + (lane&15), ch);
      #pragma unroll
      for (int m=0;m<4;m++)
        #pragma unroll
        for (int n=0;n<4;n++)
          acc[m][n] = __builtin_amdgcn_mfma_f32_16x16x32_bf16(af[m], bfr[n], acc[m][n], 0,0,0);
    }
    __syncthreads();   // drains prefetch vmcnt + lgkm, releases buffers
  }

  // fused LSTM update: gates interleaved as ncol = jj*4 + g; 4-lane shfl transpose.
  const int g = lane&3;
  float bgv[4];
  #pragma unroll
  for (int n=0;n<4;n++) bgv[n] = bgp[pb*256 + wc + n*16 + (lane&15)];
  const float s  = (g==2) ? 2.0f : -1.0f;
  const float ca = (g==2) ? -2.0f : 1.0f;
  const float cb = (g==2) ? 1.0f : 0.0f;
  #pragma unroll
  for (int m=0;m<4;m++){
    int row = r0 + wr + m*16 + ((lane>>4)<<2) + g;
    #pragma unroll
    for (int n=0;n<4;n++){
      float b = bgv[n];
      float q0 = 1.f/(1.f+__expf(s*(acc[m][n][0]+b))); float a0 = q0*ca+cb;
      float q1 = 1.f/(1.f+__expf(s*(acc[m][n][1]+b))); float a1 = q1*ca+cb;
      float q2 = 1.f/(1.f+__expf(s*(acc[m][n][2]+b))); float a2 = q2*ca+cb;
      float q3 = 1.f/(1.f+__expf(s*(acc[m][n][3]+b))); float a3 = q3*ca+cb;
      int i1=g^1, i2=g^2, i3=g^3;
      float p1 = (i1==0)?a0:(i1==1)?a1:(i1==2)?a2:a3;
      float p2 = (i2==0)?a0:(i2==1)?a1:(i2==2)?a2:a3;
      float p3 = (i3==0)?a0:(i3==1)?a1:(i3==2)?a2:a3;
      float ow = (g==0)?a0:(g==1)?a1:(g==2)?a2:a3;
      float t1 = __shfl_xor(p1, 1, 64);
      float t2 = __shfl_xor(p2, 2, 64);
      float t3 = __shfl_xor(p3, 3, 64);
      float si = (g==0)?ow:(g==1)?t1:(g==2)?t2:t3;
      float sf = (g==1)?ow:(g==0)?t1:(g==3)?t2:t3;
      float tg = (g==2)?ow:(g==3)?t1:(g==0)?t2:t3;
      float so = (g==3)?ow:(g==2)?t1:(g==1)?t2:t3;
      int jh = pb*64 + ((wc + n*16 + (lane&15))>>2);
      size_t idx = (size_t)row*Hn + jh;
      float co = c_g[idx];
      float cn = sf*co + si*tg;
      float targ = fminf(fmaxf(2.0f*cn,-60.f),60.f);
      float e = __expf(targ); float th = (e-1.f)/(e+1.f);
      c_g[idx] = cn;
      h_g[idx] = so*th;
    }
  }
}

// ---------- epilogue ----------

__global__ void k_out(const float* __restrict__ h_g, const float* __restrict__ outW,
                      const float* __restrict__ outb, const float* __restrict__ labels,
                      float* __restrict__ out_sig, float* __restrict__ yacc){
  int b = blockIdx.x, lane = threadIdx.x;
  float s = 0.f;
  for (int k = lane; k < Hn; k += 64) s += h_g[(size_t)b*Hn + k] * outW[k];
  #pragma unroll
  for (int o = 32; o > 0; o >>= 1) s += __shfl_down(s, o);
  if (lane == 0){
    float z = s + outb[0];
    out_sig[b] = sigmf_(z);
    float yl = fmaxf(z, 0.f) - z*labels[b] + log1pf(expf(-fabsf(z)));
    atomicAdd(yacc, yl);
  }
}

__global__ void k_loss(const float* __restrict__ realW, const float* __restrict__ histW,
                       const float* __restrict__ stW,   const float* __restrict__ frW,
                       const float* __restrict__ num,   const float* __restrict__ den,
                       const float* __restrict__ yacc,  float* __restrict__ out0){
  int tid = threadIdx.x;
  float r1 = 0.f;
  for (int i = tid; i < Fn*Fn; i += 256) r1 += fabsf(realW[i]);
  for (int i = tid; i < Fn*Hn; i += 256) r1 += fabsf(histW[i]);
  for (int i = tid; i < Fn*Sn; i += 256) r1 += fabsf(stW[i]);
  float rd = 0.f;
  for (int i = tid; i < Fn; i += 256) rd += fabsf(realW[i*Fn + i]);
  float fd = 0.f;
  for (int i = tid; i < Sn; i += 256) fd += fabsf(frW[i*Sn + i]);
  float xl = 0.f;
  for (int t = tid; t < Tn; t += 256) xl += num[t] / (den[t] + 1e-5f);
  float v = 0.01f*r1 + 0.1f*rd + 0.3f*xl + 0.03f*fd;
  __shared__ float red[256];
  red[tid] = v; __syncthreads();
  for (int o = 128; o > 0; o >>= 1){ if (tid < o) red[tid] += red[tid + o]; __syncthreads(); }
  if (tid == 0) out0[0] = red[0] + yacc[0] / (float)Bn;
}

// ---------- launch ----------

extern "C" void kernel_launch(void* const* d_in, const int* in_sizes, int n_in,
                              void* d_out, int out_size, void* d_ws, size_t ws_size,
                              hipStream_t stream){
  const float* values = (const float*)d_in[0];
  const float* masks  = (const float*)d_in[1];
  const float* deltas = (const float*)d_in[2];
  const float* statics= (const float*)d_in[3];
  const float* smask  = (const float*)d_in[4];
  const float* labels = (const float*)d_in[5];
  const float* frW = (const float*)d_in[6];
  const float* frb = (const float*)d_in[7];
  const float* d1W = (const float*)d_in[8];
  const float* d1b = (const float*)d_in[9];
  const float* d2W = (const float*)d_in[10];
  const float* d2b = (const float*)d_in[11];
  const float* d3W = (const float*)d_in[12];
  const float* d3b = (const float*)d_in[13];
  const float* tdW = (const float*)d_in[14];
  const float* tdb = (const float*)d_in[15];
  const float* histW = (const float*)d_in[16];
  const float* histb = (const float*)d_in[17];
  const float* stW = (const float*)d_in[18];
  const float* stb = (const float*)d_in[19];
  const float* realW = (const float*)d_in[20];
  const float* realb = (const float*)d_in[21];
  const float* Wih = (const float*)d_in[22];
  const float* Whh = (const float*)d_in[23];
  const float* bih = (const float*)d_in[24];
  const float* bhh = (const float*)d_in[25];
  const float* outW = (const float*)d_in[26];
  const float* outb = (const float*)d_in[27];

  float* out0    = (float*)d_out;
  float* out_sig = out0 + 1;
  float* out_imp = out0 + 1 + Bn;

  float* wsf  = (float*)d_ws;
  float* s_c  = wsf;  wsf += Bn*Sn;
  float* h    = wsf;  wsf += (size_t)Bn*Hn;
  float* c    = wsf;  wsf += (size_t)Bn*Hn;
  float* st   = wsf;  wsf += Bn*Fn;
  float* tmp  = wsf;  wsf += (size_t)Bn*Hn;
  float* den  = wsf;  wsf += Tn;
  float* num  = wsf;  wsf += Tn;
  float* yacc = num + Tn;           // [1], contiguous with num for one memset
  wsf += 1;
  float* bxp  = wsf;  wsf += 128;   // 96 used
  float* bgp  = wsf;  wsf += 2048;
  size_t off = ((size_t)(wsf - (float*)d_ws) + 3u) & ~(size_t)3u;
  short* wss  = (short*)((float*)d_ws + off);
  short* tdWp = wss;  wss += 512*128;
  short* Wxp  = wss;  wss += 96*640;
  short* Wgp  = wss;  wss += (size_t)8*256*704;
  short* inp  = wss;  wss += (size_t)Bn*800;

  hipMemsetAsync(c,   0, (size_t)Bn*Hn*sizeof(float), stream);
  hipMemsetAsync(num, 0, (Tn + 1)*sizeof(float), stream);

  // prepacks
  k_pack_td<<<(512*128+255)/256, 256, 0, stream>>>(tdW, tdWp);
  k_pack_x <<<(96*640+255)/256, 256, 0, stream>>>(realW, histW, realb, histb, Wxp, bxp);
  k_pack_g <<<(8*256*704+255)/256, 256, 0, stream>>>(Wih, Whh, bih, bhh, Wgp, bgp);

  // prologue math
  k_static<<<Bn, Sn, 0, stream>>>(statics, smask, frW, frb, s_c);
  k_mlp<Sn, Hn, true ><<<Bn, 256, 0, stream>>>(s_c, d1W, d1b, tmp);
  k_mlp<Hn, Hn, true ><<<Bn, 256, 0, stream>>>(tmp, d2W, d2b, tmp);
  k_mlp<Hn, Hn, true ><<<Bn, 256, 0, stream>>>(tmp, d3W, d3b, h);
  k_mlp<Sn, Fn, false><<<Bn, 256, 0, stream>>>(s_c, stW, stb, st);
  k_masksum<<<Tn, 256, 0, stream>>>(masks, den);

  for (int t = 0; t < Tn; t++){
    k_decay<<<(Bn/128)*4, 512, 0, stream>>>(t, values, masks, deltas, tdWp, tdb, h, inp);
    k_xc   <<<Bn/32,      256, 0, stream>>>(t, Wxp, bxp, st, inp, out_imp, num);
    k_gates<<<(Bn/128)*8, 512, 0, stream>>>(t, inp, Wgp, bgp, h, c);
  }

  k_out<<<Bn, 64, 0, stream>>>(h, outW, outb, labels, out_sig, yacc);
  k_loss<<<1, 256, 0, stream>>>(realW, histW, stW, frW, num, den, yacc, out0);
}